// Round 5
// baseline (165.476 us; speedup 1.0000x reference)
//
#include <hip/hip_runtime.h>
#include <math.h>

#define NTOK 16384      // 4 * 4096 tokens
#define DIM 2048
#define NEXP 64
#define TOPK 8
#define BT 32           // tokens per block
#define KC 64           // four numpy 16-blocks per LDS stage (processed in order)
#define NCHUNK (DIM / KC)   // 32
#define PADK 68         // LDS row stride (floats), 16B-aligned, bank-spread
#define NBLK (NTOK / BT)    // 512 blocks

typedef float f2 __attribute__((ext_vector_type(2)));
typedef float f4 __attribute__((ext_vector_type(4)));

// Packed f32 ops: two independent IEEE f32 ops per instr, component-wise
// bit-identical to the scalar sequence they replace (no fusion, no reassoc).
__device__ __forceinline__ f2 pk_mul(f2 a, f2 b) {
    f2 d; asm("v_pk_mul_f32 %0, %1, %2" : "=v"(d) : "v"(a), "v"(b)); return d;
}
__device__ __forceinline__ f2 pk_add(f2 a, f2 b) {
    f2 d; asm("v_pk_add_f32 %0, %1, %2" : "=v"(d) : "v"(a), "v"(b)); return d;
}

__global__ __launch_bounds__(256, 2) void moe_gate_np(
    const float* __restrict__ h, const float* __restrict__ W,
    float* __restrict__ out, float* __restrict__ wsum)
{
#pragma clang fp contract(off)
    __shared__ float sA[BT * PADK];          // h tile   [32][68]
    __shared__ float sB[NEXP * PADK];        // W tile   [64][68]
    __shared__ float lg[BT][NEXP + 2];       // logits -> p values

    const int tid = threadIdx.x;
    const int blk = blockIdx.x;
    const long tok0 = (long)blk * BT;
    const float* hA = h + tok0 * DIM;

    // ---- staging maps ----
    const int rA = tid >> 3;                 // 0..31
    const int cA = (tid & 7) * 8;            // 0..56, 2 float4 each
    const int rB = tid >> 2;                 // 0..63
    const int cB = (tid & 3) * 16;           // 0..48, 4 float4 each

    f4 pa[2], pb[4];
    #pragma unroll
    for (int q = 0; q < 2; ++q) pa[q] = *(const f4*)(hA + (long)rA * DIM + cA + 4 * q);
    #pragma unroll
    for (int q = 0; q < 4; ++q) pb[q] = *(const f4*)(W + (long)rB * DIM + cB + 4 * q);

    // ---- compute map: 2 tokens x 4 experts per thread ----
    const int tx = tid & 15;                 // expert base
    const int ty = tid >> 4;                 // token base (0..15)

    // chain pairs: axy = (chain_x, chain_y), azw = (chain_z, chain_w)
    f2 axy[2][4], azw[2][4];
    #pragma unroll
    for (int i = 0; i < 2; ++i)
        #pragma unroll
        for (int j = 0; j < 4; ++j) { axy[i][j] = (f2)(0.f); azw[i][j] = (f2)(0.f); }

    for (int kc = 0; kc < NCHUNK; ++kc) {
        __syncthreads();
        #pragma unroll
        for (int q = 0; q < 2; ++q) *(f4*)&sA[rA * PADK + cA + 4 * q] = pa[q];
        #pragma unroll
        for (int q = 0; q < 4; ++q) *(f4*)&sB[rB * PADK + cB + 4 * q] = pb[q];
        __syncthreads();

        if (kc + 1 < NCHUNK) {               // prefetch next stage under compute
            const long ko = (long)(kc + 1) * KC;
            #pragma unroll
            for (int q = 0; q < 2; ++q) pa[q] = *(const f4*)(hA + (long)rA * DIM + ko + cA + 4 * q);
            #pragma unroll
            for (int q = 0; q < 4; ++q) pb[q] = *(const f4*)(W + (long)rB * DIM + ko + cB + 4 * q);
        }

        // 4 numpy 16-blocks, strictly in k order
        #pragma unroll
        for (int s = 0; s < 4; ++s) {
            f2 alo[2][4], ahi[2][4], blo[4][4], bhi[4][4];
            #pragma unroll
            for (int i = 0; i < 2; ++i) {
                const float* base = &sA[(ty + 16 * i) * PADK + s * 16];
                #pragma unroll
                for (int v = 0; v < 4; ++v) {
                    f4 a = *(const f4*)(base + 4 * v);
                    alo[i][v] = __builtin_shufflevector(a, a, 0, 1);
                    ahi[i][v] = __builtin_shufflevector(a, a, 2, 3);
                }
            }
            #pragma unroll
            for (int j = 0; j < 4; ++j) {
                const float* base = &sB[(tx + 16 * j) * PADK + s * 16];
                #pragma unroll
                for (int v = 0; v < 4; ++v) {
                    f4 b = *(const f4*)(base + 4 * v);
                    blo[j][v] = __builtin_shufflevector(b, b, 0, 1);
                    bhi[j][v] = __builtin_shufflevector(b, b, 2, 3);
                }
            }
            #pragma unroll
            for (int i = 0; i < 2; ++i)
                #pragma unroll
                for (int j = 0; j < 4; ++j) {
                    f2 t;
                    // chains x,y:  c = p0 + (p1 + (p2 + (p3 + c)))
                    t = pk_add(pk_mul(alo[i][3], blo[j][3]), axy[i][j]);
                    t = pk_add(pk_mul(alo[i][2], blo[j][2]), t);
                    t = pk_add(pk_mul(alo[i][1], blo[j][1]), t);
                    axy[i][j] = pk_add(pk_mul(alo[i][0], blo[j][0]), t);
                    // chains z,w
                    t = pk_add(pk_mul(ahi[i][3], bhi[j][3]), azw[i][j]);
                    t = pk_add(pk_mul(ahi[i][2], bhi[j][2]), t);
                    t = pk_add(pk_mul(ahi[i][1], bhi[j][1]), t);
                    azw[i][j] = pk_add(pk_mul(ahi[i][0], bhi[j][0]), t);
                }
        }
    }

    // horizontal combine: (x+z)+(y+w) — pk_add gives (x+z, y+w), then scalar add
    #pragma unroll
    for (int i = 0; i < 2; ++i)
        #pragma unroll
        for (int j = 0; j < 4; ++j) {
            f2 s2 = pk_add(axy[i][j], azw[i][j]);
            lg[ty + 16 * i][tx + 16 * j] = s2.x + s2.y;
        }
    __syncthreads();

    // ---- per-token f32 softmax + stable top-8, numpy rounding orders ----
    const int lane = tid & 63;
    const int wv   = tid >> 6;               // 4 waves, 8 tokens each
    float auxacc = 0.f;

    for (int tt = 0; tt < 8; ++tt) {
        const int t = wv * 8 + tt;
        const float s = lg[t][lane];

        float m = s;                          // max: exact, order-independent
        #pragma unroll
        for (int off = 32; off >= 1; off >>= 1)
            m = fmaxf(m, __shfl_xor(m, off));

        const float p = expf(s - m);
        lg[t][lane] = p;                      // own wave's row only
        __asm__ volatile("" ::: "memory");    // compiler barrier; DS in-order per wave

        // np.sum pairwise, n=64: 8 stride-8 serial chains + fixed combine
        float r0 = lg[t][0], r1 = lg[t][1], r2 = lg[t][2], r3 = lg[t][3];
        float r4 = lg[t][4], r5 = lg[t][5], r6 = lg[t][6], r7 = lg[t][7];
        #pragma unroll
        for (int i = 1; i < 8; ++i) {
            r0 += lg[t][8 * i + 0]; r1 += lg[t][8 * i + 1];
            r2 += lg[t][8 * i + 2]; r3 += lg[t][8 * i + 3];
            r4 += lg[t][8 * i + 4]; r5 += lg[t][8 * i + 5];
            r6 += lg[t][8 * i + 6]; r7 += lg[t][8 * i + 7];
        }
        const float S = ((r0 + r1) + (r2 + r3)) + ((r4 + r5) + (r6 + r7));

        const float score = p / S;            // IEEE f32 divide, matches np
        auxacc += score;

        // stable top-8: max with lowest-index tie-break (stable argsort)
        float cv = score;
        float myv = 0.f;
        int   myi = 0;
        #pragma unroll
        for (int i = 0; i < TOPK; ++i) {
            float v = cv;
            int idx = lane;
            #pragma unroll
            for (int off = 32; off >= 1; off >>= 1) {
                float v2 = __shfl_xor(v, off);
                int   i2 = __shfl_xor(idx, off);
                if (v2 > v || (v2 == v && i2 < idx)) { v = v2; idx = i2; }
            }
            if (lane == i)   { myv = v; myi = idx; }
            if (lane == idx) cv = -1.f;       // scores >= 0
        }

        // weight denom: np.sum n=8 -> serial ascending
        float S8 = 0.f;
        #pragma unroll
        for (int r = 0; r < TOPK; ++r) S8 += __shfl(myv, r);

        if (lane < TOPK) {
            const long o = (tok0 + t) * TOPK + lane;
            out[o]                     = (float)myi;   // expert_ids
            out[(long)NTOK * TOPK + o] = myv / S8;     // expert_weight
        }
    }

    const int b = blk >> 7;                  // 128 blocks per batch row
    atomicAdd(&wsum[b * NEXP + lane], auxacc);
}

__global__ void aux_finish(const float* __restrict__ wsum, float* __restrict__ out)
{
    const int lane = threadIdx.x;            // 64 threads
    float a = 0.f;
    #pragma unroll
    for (int b = 0; b < 4; ++b) {
        const float v = wsum[b * NEXP + lane] * (1.0f / 4096.0f);
        a = fmaf(v, v, a);
    }
    #pragma unroll
    for (int off = 32; off >= 1; off >>= 1)
        a += __shfl_xor(a, off);
    if (lane == 0)
        out[2L * NTOK * TOPK] = a * 0.25f * (float)NEXP * 0.01f;
}

extern "C" void kernel_launch(void* const* d_in, const int* in_sizes, int n_in,
                              void* d_out, int out_size, void* d_ws, size_t ws_size,
                              hipStream_t stream) {
    const float* h = (const float*)d_in[0];
    const float* W = (const float*)d_in[1];
    float* out  = (float*)d_out;
    float* wsum = (float*)d_ws;              // 256 f32

    hipMemsetAsync(d_ws, 0, 1024, stream);
    moe_gate_np<<<NBLK, 256, 0, stream>>>(h, W, out, wsum);
    aux_finish<<<1, 64, 0, stream>>>(wsum, out);
}